// Round 2
// baseline (444.470 us; speedup 1.0000x reference)
//
#include <hip/hip_runtime.h>

#define NV 15000
#define ND 16
#define NR 3
#define NC 32
#define NFDIM 64
#define BB 2

typedef short bf16x8 __attribute__((ext_vector_type(8)));
typedef float f32x4 __attribute__((ext_vector_type(4)));
typedef unsigned short u16x8 __attribute__((ext_vector_type(8)));
typedef unsigned int u32;

// ws layout (bytes):
//   y_t  bf16 [NV][16][2][32]          : 30,720,000
//   kb   bf16 [48][4][64][8]           :    196,608
#define KB_OFF     30720000u
#define WS_NEEDED  30916608u

#define AS1 __attribute__((address_space(1)))
#define AS3 __attribute__((address_space(3)))
#define GLOAD16(gp, lp) __builtin_amdgcn_global_load_lds((AS1 const u32*)(gp), (AS3 u32*)(lp), 16, 0, 0)

__device__ __forceinline__ unsigned short f2bf(float x) {
  union { float f; unsigned int u; } cv; cv.f = x;
  unsigned int u = cv.u;
  u += 0x7FFF + ((u >> 16) & 1);          // round to nearest even
  return (unsigned short)(u >> 16);
}

// y (B,NV,16,32) fp32 -> y_t (NV,16,B,32) bf16. One thread per 8 elems.
__global__ void prep_y(const float* __restrict__ y, u16x8* __restrict__ yt) {
  int tid = blockIdx.x * 256 + threadIdx.x;
  if (tid >= (NV * ND * BB * NC) / 8) return;
  int o   = tid * 8;
  int v   = o >> 10;
  int rem = o & 1023;
  int d   = rem >> 6;
  int b   = (rem >> 5) & 1;
  int c0  = rem & 31;
  const f32x4* src = (const f32x4*)(y + (((b * NV + v) * ND + d) * NC + c0));
  f32x4 lo = src[0], hi = src[1];
  u16x8 r;
#pragma unroll
  for (int i = 0; i < 4; i++) { r[i] = f2bf(lo[i]); r[4 + i] = f2bf(hi[i]); }
  yt[tid] = r;
}

// kernel (3,16,32,64) fp32 -> kb in MFMA B-fragment layout with f = 4*col+ft:
// kb[((chunk*4 + ft)*64 + lane)*8 + j] = kernel[chunk][k=(lane>>4)*8+j][f=(lane&15)*4+ft]
__global__ void prep_kb(const float* __restrict__ kern, unsigned short* __restrict__ kb) {
  int t = blockIdx.x * 256 + threadIdx.x;   // [0, 48*4*64)
  if (t >= 48 * 4 * 64) return;
  int lane  = t & 63;
  int ft    = (t >> 6) & 3;
  int chunk = t >> 8;
  int q = lane >> 4;
  int f = (lane & 15) * 4 + ft;
  unsigned short* dst = kb + t * 8;
#pragma unroll
  for (int j = 0; j < 8; j++) {
    int k = q * 8 + j;
    dst[j] = f2bf(kern[(chunk * NC + k) * NFDIM + f]);
  }
}

// R6: LDS-ring pipeline (T3/T4 structure, m201/m218 pattern).
//  - R4/R5 post-mortem: register-resident double-buffering collapses in
//    regalloc (VGPR stayed 64/84, MfmaUtil 18%, ~4400cyc/batch vs 78cyc MFMA).
//    Flight depth now lives in LDS + the vmcnt counter, not registers.
//  - Per s-step (48 total): A = 2 x global_load_lds (random per-lane gather
//    addr, lane-linear LDS dest == MFMA fragment order); B = 1 x
//    global_load_lds per wave (wave w stages ft=w) into a BLOCK-SHARED slot
//    (kb stream is block-uniform thanks to the e-reorder) -> B L2 traffic /4.
//  - Ring depth D=5 slots (12KB/slot; LDS total 64,576B -> 2 blocks/CU).
//    Steady state: wait vmcnt(9) (3 slots in flight, never drained to 0),
//    THEN s_barrier (certifies all waves' slot-t loads incl. B shares),
//    then stage(t+4) into slot (t-1)%5 (dead: everyone computed t-1 before
//    this barrier), then compute(t): 6 ds_read_b128 + 8 MFMA.
__global__ __launch_bounds__(256, 2) void sync_conv_main(
    const unsigned short* __restrict__ yt, const unsigned short* __restrict__ kb,
    const int* __restrict__ ftv, const int* __restrict__ ftd,
    const float* __restrict__ bias, float* __restrict__ out) {
  __shared__ short lds_a[5 * 4 * 2 * 512];   // [slot][w][mt][512]  40,960 B
  __shared__ short lds_b[5 * 4 * 512];       // [slot][ft][512]     20,480 B
  __shared__ int   pidx[16][49];             //                      3,136 B

  int tid  = threadIdx.x;
  int lane = tid & 63;
  int w    = tid >> 6;
  int mg   = blockIdx.x >> 2;
  int lg   = blockIdx.x & 3;
  int l    = lg * 4 + w;
  int vbase = mg * 16;

  for (int t = tid; t < 16 * 48; t += 256) {
    int i = t / 48, j = t - i * 48;
    int v = vbase + i; v = v < NV ? v : NV - 1;
    pidx[i][j] = ftv[v * 48 + j] * 16 + (ftd[v * 48 + j] & 15);
  }
  __syncthreads();

  int q    = lane >> 4;
  int n    = lane & 15;
  int voff = n >> 1;
  int lane_elem = (n & 1) * 32 + q * 8;     // shorts; *2 = 16B-aligned bytes
  const int* rp0 = &pidx[voff][0];
  const int* rp1 = &pidx[8 + voff][0];

  f32x4 acc[2][4];
#pragma unroll
  for (int i = 0; i < 2; i++)
#pragma unroll
    for (int j = 0; j < 4; j++) acc[i][j] = (f32x4){0.f, 0.f, 0.f, 0.f};

  // stage s-step s into ring slot ss
  auto stage = [&](int s, int ss) {
    int j  = (s & 48) | ((s + l) & 15);      // entry column for this wave
    int p0 = rp0[j];
    int p1 = rp1[j];
    int off0 = ((p0 >> 4) << 10) | ((((p0 & 15) + l) & 15) << 6);
    int off1 = ((p1 >> 4) << 10) | ((((p1 & 15) + l) & 15) << 6);
    const unsigned short* g0 = yt + off0 + lane_elem;
    const unsigned short* g1 = yt + off1 + lane_elem;
    short* la = lds_a + (ss * 4 + w) * 1024;
    GLOAD16(g0, la);
    GLOAD16(g1, la + 512);
    const unsigned short* gb = kb + s * 2048 + w * 512 + (lane << 3);
    GLOAD16(gb, lds_b + (ss * 4 + w) * 512);
  };

  auto computeP = [&](int cs) {
    const short* la = lds_a + (cs * 4 + w) * 1024;
    const short* lb = lds_b + cs * 2048;
    bf16x8 a0 = *(const bf16x8*)(la + (lane << 3));
    bf16x8 a1 = *(const bf16x8*)(la + 512 + (lane << 3));
    __builtin_amdgcn_s_setprio(1);
#pragma unroll
    for (int ft = 0; ft < 4; ft++) {
      bf16x8 bf = *(const bf16x8*)(lb + ft * 512 + (lane << 3));
      acc[0][ft] = __builtin_amdgcn_mfma_f32_16x16x32_bf16(a0, bf, acc[0][ft], 0, 0, 0);
      acc[1][ft] = __builtin_amdgcn_mfma_f32_16x16x32_bf16(a1, bf, acc[1][ft], 0, 0, 0);
    }
    __builtin_amdgcn_s_setprio(0);
  };

  // Prologue: fill 4 slots (12 loads in flight per wave).
  stage(0, 0); stage(1, 1); stage(2, 2); stage(3, 3);

  int cs = 0, ss = 4;
  for (int t = 0; t < 44; t++) {
    asm volatile("s_waitcnt vmcnt(9)" ::: "memory");
    __builtin_amdgcn_s_barrier();
    stage(t + 4, ss);
    computeP(cs);
    cs = cs == 4 ? 0 : cs + 1;
    ss = ss == 4 ? 0 : ss + 1;
  }
  // Tail: drain 4 remaining slots.
  asm volatile("s_waitcnt vmcnt(9)" ::: "memory");
  __builtin_amdgcn_s_barrier();
  computeP(cs); cs = cs == 4 ? 0 : cs + 1;
  asm volatile("s_waitcnt vmcnt(6)" ::: "memory");
  __builtin_amdgcn_s_barrier();
  computeP(cs); cs = cs == 4 ? 0 : cs + 1;
  asm volatile("s_waitcnt vmcnt(3)" ::: "memory");
  __builtin_amdgcn_s_barrier();
  computeP(cs); cs = cs == 4 ? 0 : cs + 1;
  asm volatile("s_waitcnt vmcnt(0)" ::: "memory");
  __builtin_amdgcn_s_barrier();
  computeP(cs);

  f32x4 bv = *reinterpret_cast<const f32x4*>(bias + 4 * n);

#pragma unroll
  for (int mt = 0; mt < 2; mt++) {
#pragma unroll
    for (int reg = 0; reg < 4; reg++) {
      int m  = q * 4 + reg;
      int v  = vbase + mt * 8 + (m >> 1);
      int bb = m & 1;
      if (v < NV) {
        f32x4 x;
#pragma unroll
        for (int ft = 0; ft < 4; ft++) {
          float t = acc[mt][ft][reg] + bv[ft];   // f = 4n+ft
          x[ft] = t > 0.f ? t : 0.f;
        }
        float* dst = out + (((bb * NV + v) * ND + l) * NFDIM) + 4 * n;
        __builtin_nontemporal_store(x, (f32x4*)dst);
      }
    }
  }
}

// Slow fp32 fallback (only if ws too small).
__global__ void fallback_kernel(const float* __restrict__ y, const int* __restrict__ ftv,
                                const int* __restrict__ ftd, const float* __restrict__ kern,
                                const float* __restrict__ bias, float* __restrict__ out) {
  int idx = blockIdx.x;               // b*NV*16 + v*16 + l
  int l = idx & 15;
  int v = (idx >> 4) % NV;
  int b = idx / (NV * ND);
  int f = threadIdx.x;
  float acc = 0.f;
  for (int r = 0; r < NR; r++)
    for (int d = 0; d < ND; d++) {
      int ii = (v * NR + r) * ND + d;
      int vv = ftv[ii];
      int dd = (ftd[ii] + l) & 15;
      int dp = (d - l) & 15;
      const float* yp = y + ((b * NV + vv) * ND + dd) * NC;
      const float* kp = kern + ((r * 16 + dp) * NC) * NFDIM + f;
#pragma unroll 8
      for (int c = 0; c < NC; c++) acc += yp[c] * kp[c * NFDIM];
    }
  float x = acc + bias[f];
  out[idx * NFDIM + f] = x > 0.f ? x : 0.f;
}

extern "C" void kernel_launch(void* const* d_in, const int* in_sizes, int n_in,
                              void* d_out, int out_size, void* d_ws, size_t ws_size,
                              hipStream_t stream) {
  const float* y    = (const float*)d_in[0];
  const int*   ftv  = (const int*)d_in[1];
  const int*   ftd  = (const int*)d_in[2];
  const float* kern = (const float*)d_in[3];
  const float* bias = (const float*)d_in[4];
  float* out = (float*)d_out;

  if (ws_size >= (size_t)WS_NEEDED) {
    char* ws = (char*)d_ws;
    unsigned short* yt = (unsigned short*)ws;
    unsigned short* kb = (unsigned short*)(ws + KB_OFF);

    prep_y<<<(NV * ND * BB * NC / 8 + 255) / 256, 256, 0, stream>>>(y, (u16x8*)yt);
    prep_kb<<<(48 * 4 * 64 + 255) / 256, 256, 0, stream>>>(kern, kb);
    // 938 m-groups (16 v each) x 4 l-groups = 3752 blocks x 4 waves
    sync_conv_main<<<3752, 256, 0, stream>>>(yt, kb, ftv, ftd, bias, out);
  } else {
    fallback_kernel<<<BB * NV * ND, NFDIM, 0, stream>>>(y, ftv, ftd, kern, bias, out);
  }
}

// Round 4
// 364.701 us; speedup vs baseline: 1.2187x; 1.2187x over previous
//
#include <hip/hip_runtime.h>

#define NV 15000
#define ND 16
#define NR 3
#define NC 32
#define NFDIM 64
#define BB 2

typedef short bf16x8 __attribute__((ext_vector_type(8)));
typedef float f32x4 __attribute__((ext_vector_type(4)));
typedef unsigned short u16x8 __attribute__((ext_vector_type(8)));
typedef unsigned int u32;

// ws layout (bytes):
//   y_t  bf16 [NV][16][2][32]          : 30,720,000
//   kb   bf16 [48][4][64][8]           :    196,608
#define KB_OFF     30720000u
#define WS_NEEDED  30916608u

#define AS1 __attribute__((address_space(1)))
#define AS3 __attribute__((address_space(3)))
#define GLOAD16(gp, lp) __builtin_amdgcn_global_load_lds((AS1 const u32*)(gp), (AS3 u32*)(lp), 16, 0, 0)

__device__ __forceinline__ unsigned short f2bf(float x) {
  union { float f; unsigned int u; } cv; cv.f = x;
  unsigned int u = cv.u;
  u += 0x7FFF + ((u >> 16) & 1);          // round to nearest even
  return (unsigned short)(u >> 16);
}

// y (B,NV,16,32) fp32 -> y_t (NV,16,B,32) bf16. One thread per 8 elems.
__global__ void prep_y(const float* __restrict__ y, u16x8* __restrict__ yt) {
  int tid = blockIdx.x * 256 + threadIdx.x;
  if (tid >= (NV * ND * BB * NC) / 8) return;
  int o   = tid * 8;
  int v   = o >> 10;
  int rem = o & 1023;
  int d   = rem >> 6;
  int b   = (rem >> 5) & 1;
  int c0  = rem & 31;
  const f32x4* src = (const f32x4*)(y + (((b * NV + v) * ND + d) * NC + c0));
  f32x4 lo = src[0], hi = src[1];
  u16x8 r;
#pragma unroll
  for (int i = 0; i < 4; i++) { r[i] = f2bf(lo[i]); r[4 + i] = f2bf(hi[i]); }
  yt[tid] = r;
}

// kernel (3,16,32,64) fp32 -> kb in MFMA B-fragment layout with f = 4*col+ft:
// kb[((chunk*4 + ft)*64 + lane)*8 + j] = kernel[chunk][k=(lane>>4)*8+j][f=(lane&15)*4+ft]
__global__ void prep_kb(const float* __restrict__ kern, unsigned short* __restrict__ kb) {
  int t = blockIdx.x * 256 + threadIdx.x;   // [0, 48*4*64)
  if (t >= 48 * 4 * 64) return;
  int lane  = t & 63;
  int ft    = (t >> 6) & 3;
  int chunk = t >> 8;
  int q = lane >> 4;
  int f = (lane & 15) * 4 + ft;
  unsigned short* dst = kb + t * 8;
#pragma unroll
  for (int j = 0; j < 8; j++) {
    int k = q * 8 + j;
    dst[j] = f2bf(kern[(chunk * NC + k) * NFDIM + f]);
  }
}

// R8 == R7 with the global_load_lds addressing bug fixed.
//
// R7 post-mortem: gl_lds writes LDS at wave-uniform-base + lane*16B (m104);
// R7's B-stage used a 32B per-lane GLOBAL stride with two interleaved 16B
// loads -> scrambled LDS image -> absmax inf. Fix: per-lane global stride ==
// 16B, each load covers a contiguous 1024B half, LDS base wave-uniform.
//
// Structure (unchanged from R7):
//  - A: direct-to-VGPR random gather (R5 path: e-reorder + pre-rotated LDS
//    offset tables).
//  - B: block-cooperative LDS ring. kb stream is block-uniform (e-reorder),
//    so the block stages each 8KB batch ONCE (2 gl_lds/wave) instead of each
//    wave pulling 8KB from L2: 64 -> 16 L1-line transactions per batch-wave.
//    Total 96 -> 48 lines/batch-wave; L1 ~4cy/line cap predicts ~113us floor.
//  - Ring: 3 batch-slots x 8KB. Iter t: vmcnt(2) (certifies slot t landed;
//    in-order retirement: B(t) is older than the already-drained A(t-1)) ->
//    s_barrier -> A(t) gather loads -> stage B(t+2) into slot (t-1)%3 (dead)
//    -> ds_read B + 16 MFMA (setprio-wrapped).
__global__ __launch_bounds__(256, 4) void sync_conv_main(
    const unsigned short* __restrict__ yt, const unsigned short* __restrict__ kb,
    const int* __restrict__ ftv, const int* __restrict__ ftd,
    const float* __restrict__ bias, float* __restrict__ out) {
  __shared__ int   pidx[16][49];     // packed ftv*16+ftd          3,136 B
  __shared__ int   pre[4][16][49];   // per-wave rotated offsets  12,544 B
  __shared__ short lds_b[3 * 4096];  // B ring, 3 batch-slots     24,576 B

  int tid  = threadIdx.x;
  int lane = tid & 63;
  int w    = tid >> 6;
  int mg   = blockIdx.x >> 2;
  int lg   = blockIdx.x & 3;
  int l    = lg * 4 + w;
  int vbase = mg * 16;

  // phase 1: packed indices
  for (int t = tid; t < 16 * 48; t += 256) {
    int i = t / 48, j = t - i * 48;
    int v = vbase + i; v = v < NV ? v : NV - 1;
    pidx[i][j] = ftv[v * 48 + j] * 16 + (ftd[v * 48 + j] & 15);
  }
  __syncthreads();
  // phase 2: per-l pre-rotated element offsets: vtx*1024 + ((ftd+l)&15)*64
#pragma unroll
  for (int wl = 0; wl < 4; wl++) {
    int ll = lg * 4 + wl;
    for (int t = tid; t < 768; t += 256) {
      int i = t / 48, j = t - i * 48;
      int p = pidx[i][j];
      pre[wl][i][j] = (p >> 4) * 1024 + ((((p & 15) + ll) & 15) << 6);
    }
  }
  __syncthreads();

  int q    = lane >> 4;
  int n    = lane & 15;
  int voff = n >> 1;
  int lane_elem = (n & 1) * 32 + q * 8;     // shorts
  const int* pre_w0 = &pre[w][voff][0];
  const int* pre_w1 = &pre[w][8 + voff][0];

  f32x4 acc[2][4];
#pragma unroll
  for (int i = 0; i < 2; i++)
#pragma unroll
    for (int j = 0; j < 4; j++) acc[i][j] = (f32x4){0.f, 0.f, 0.f, 0.f};

  // Cooperative B-stage: batch t = chunks {2t, 2t+1} = 8 KB; wave w stages
  // its contiguous 2 KB quarter as two 1024-B lane-linear gl_lds loads.
  // Per-lane global stride = 16 B = gl_lds lane stride; LDS base uniform.
  auto stageB = [&](int t, int slot) {
    const unsigned short* g = kb + t * 4096 + w * 1024 + (lane << 3);
    short* d = lds_b + slot * 4096 + w * 1024;
    GLOAD16(g, d);
    GLOAD16(g + 512, d + 512);
  };

  // Prologue: slots 0 and 1 in flight.
  stageB(0, 0);
  stageB(1, 1);

  int sl = 0;                                  // slot of batch t
#pragma unroll 3
  for (int t = 0; t < 24; t++) {
    if (t < 23) {
      asm volatile("s_waitcnt vmcnt(2)" ::: "memory");
    } else {
      asm volatile("s_waitcnt vmcnt(0)" ::: "memory");
    }
    __builtin_amdgcn_s_barrier();

    // A gather for this batch (direct to VGPR) — issue before B-stage.
    bf16x8 A[2][2];
#pragma unroll
    for (int ds = 0; ds < 2; ds++) {
      int s = 2 * t + ds;
      int j = (s & 48) | ((s + l) & 15);       // r*16 + ((e+l)&15)
      A[0][ds] = *reinterpret_cast<const bf16x8*>(yt + pre_w0[j] + lane_elem);
      A[1][ds] = *reinterpret_cast<const bf16x8*>(yt + pre_w1[j] + lane_elem);
    }

    if (t + 2 < 24) stageB(t + 2, sl == 0 ? 2 : sl - 1);   // (t+2)%3 == (t-1)%3

    const short* lb = lds_b + sl * 4096;
    __builtin_amdgcn_s_setprio(1);
#pragma unroll
    for (int ds = 0; ds < 2; ds++) {
#pragma unroll
      for (int ft = 0; ft < 4; ft++) {
        bf16x8 bf = *reinterpret_cast<const bf16x8*>(lb + ds * 2048 + ft * 512 + (lane << 3));
        acc[0][ft] = __builtin_amdgcn_mfma_f32_16x16x32_bf16(A[0][ds], bf, acc[0][ft], 0, 0, 0);
        acc[1][ft] = __builtin_amdgcn_mfma_f32_16x16x32_bf16(A[1][ds], bf, acc[1][ft], 0, 0, 0);
      }
    }
    __builtin_amdgcn_s_setprio(0);
    sl = sl == 2 ? 0 : sl + 1;
  }

  f32x4 bv = *reinterpret_cast<const f32x4*>(bias + 4 * n);

#pragma unroll
  for (int mt = 0; mt < 2; mt++) {
#pragma unroll
    for (int reg = 0; reg < 4; reg++) {
      int m  = q * 4 + reg;
      int v  = vbase + mt * 8 + (m >> 1);
      int bb = m & 1;
      if (v < NV) {
        f32x4 x;
#pragma unroll
        for (int ft = 0; ft < 4; ft++) {
          float t = acc[mt][ft][reg] + bv[ft];   // f = 4n+ft
          x[ft] = t > 0.f ? t : 0.f;
        }
        float* dst = out + (((bb * NV + v) * ND + l) * NFDIM) + 4 * n;
        __builtin_nontemporal_store(x, (f32x4*)dst);
      }
    }
  }
}

// Slow fp32 fallback (only if ws too small).
__global__ void fallback_kernel(const float* __restrict__ y, const int* __restrict__ ftv,
                                const int* __restrict__ ftd, const float* __restrict__ kern,
                                const float* __restrict__ bias, float* __restrict__ out) {
  int idx = blockIdx.x;               // b*NV*16 + v*16 + l
  int l = idx & 15;
  int v = (idx >> 4) % NV;
  int b = idx / (NV * ND);
  int f = threadIdx.x;
  float acc = 0.f;
  for (int r = 0; r < NR; r++)
    for (int d = 0; d < ND; d++) {
      int ii = (v * NR + r) * ND + d;
      int vv = ftv[ii];
      int dd = (ftd[ii] + l) & 15;
      int dp = (d - l) & 15;
      const float* yp = y + ((b * NV + vv) * ND + dd) * NC;
      const float* kp = kern + ((r * 16 + dp) * NC) * NFDIM + f;
#pragma unroll 8
      for (int c = 0; c < NC; c++) acc += yp[c] * kp[c * NFDIM];
    }
  float x = acc + bias[f];
  out[idx * NFDIM + f] = x > 0.f ? x : 0.f;
}

extern "C" void kernel_launch(void* const* d_in, const int* in_sizes, int n_in,
                              void* d_out, int out_size, void* d_ws, size_t ws_size,
                              hipStream_t stream) {
  const float* y    = (const float*)d_in[0];
  const int*   ftv  = (const int*)d_in[1];
  const int*   ftd  = (const int*)d_in[2];
  const float* kern = (const float*)d_in[3];
  const float* bias = (const float*)d_in[4];
  float* out = (float*)d_out;

  if (ws_size >= (size_t)WS_NEEDED) {
    char* ws = (char*)d_ws;
    unsigned short* yt = (unsigned short*)ws;
    unsigned short* kb = (unsigned short*)(ws + KB_OFF);

    prep_y<<<(NV * ND * BB * NC / 8 + 255) / 256, 256, 0, stream>>>(y, (u16x8*)yt);
    prep_kb<<<(48 * 4 * 64 + 255) / 256, 256, 0, stream>>>(kern, kb);
    // 938 m-groups (16 v each) x 4 l-groups = 3752 blocks x 4 waves
    sync_conv_main<<<3752, 256, 0, stream>>>(yt, kb, ftv, ftd, bias, out);
  } else {
    fallback_kernel<<<BB * NV * ND, NFDIM, 0, stream>>>(y, ftv, ftd, kern, bias, out);
  }
}

// Round 5
// 363.404 us; speedup vs baseline: 1.2231x; 1.0036x over previous
//
#include <hip/hip_runtime.h>

#define NV 15000
#define ND 16
#define NR 3
#define NC 32
#define NFDIM 64
#define BB 2

typedef short bf16x8 __attribute__((ext_vector_type(8)));
typedef float f32x4 __attribute__((ext_vector_type(4)));
typedef unsigned short u16x8 __attribute__((ext_vector_type(8)));
typedef unsigned int u32;

// ws layout (bytes):
//   y_t  bf16 [NV][16][2][32]          : 30,720,000
//   kb   bf16 [48][4][64][8]           :    196,608
#define KB_OFF     30720000u
#define WS_NEEDED  30916608u

#define AS1 __attribute__((address_space(1)))
#define AS3 __attribute__((address_space(3)))
#define GLOAD16(gp, lp) __builtin_amdgcn_global_load_lds((AS1 const u32*)(gp), (AS3 u32*)(lp), 16, 0, 0)

__device__ __forceinline__ unsigned short f2bf(float x) {
  union { float f; unsigned int u; } cv; cv.f = x;
  unsigned int u = cv.u;
  u += 0x7FFF + ((u >> 16) & 1);          // round to nearest even
  return (unsigned short)(u >> 16);
}

// y (B,NV,16,32) fp32 -> y_t (NV,16,B,32) bf16. One thread per 8 elems.
__global__ void prep_y(const float* __restrict__ y, u16x8* __restrict__ yt) {
  int tid = blockIdx.x * 256 + threadIdx.x;
  if (tid >= (NV * ND * BB * NC) / 8) return;
  int o   = tid * 8;
  int v   = o >> 10;
  int rem = o & 1023;
  int d   = rem >> 6;
  int b   = (rem >> 5) & 1;
  int c0  = rem & 31;
  const f32x4* src = (const f32x4*)(y + (((b * NV + v) * ND + d) * NC + c0));
  f32x4 lo = src[0], hi = src[1];
  u16x8 r;
#pragma unroll
  for (int i = 0; i < 4; i++) { r[i] = f2bf(lo[i]); r[4 + i] = f2bf(hi[i]); }
  yt[tid] = r;
}

// kernel (3,16,32,64) fp32 -> kb in MFMA B-fragment layout with f = 4*col+ft:
// kb[((chunk*4 + ft)*64 + lane)*8 + j] = kernel[chunk][k=(lane>>4)*8+j][f=(lane&15)*4+ft]
__global__ void prep_kb(const float* __restrict__ kern, unsigned short* __restrict__ kb) {
  int t = blockIdx.x * 256 + threadIdx.x;   // [0, 48*4*64)
  if (t >= 48 * 4 * 64) return;
  int lane  = t & 63;
  int ft    = (t >> 6) & 3;
  int chunk = t >> 8;
  int q = lane >> 4;
  int f = (lane & 15) * 4 + ft;
  unsigned short* dst = kb + t * 8;
#pragma unroll
  for (int j = 0; j < 8; j++) {
    int k = q * 8 + j;
    dst[j] = f2bf(kern[(chunk * NC + k) * NFDIM + f]);
  }
}

// R9: R8 + depth-2 A-register-prefetch + LDS shrink (pidx aliased over ring).
//
// R8 post-mortem: cutting B's L2 traffic 4x bought only 5%. Invariant across
// R0/R5/R8: ~765 MB L2-miss traffic at 3.5-3.8 TB/s. Two candidate binding
// models: (1) fabric/L3 random-line rate cap (nothing helps but fewer bytes —
// structurally impossible here; fp8 fails absmax); (2) concurrent-miss limit
// (R8 drains all 4 A-loads inside every iter; only wave-TLP hides latency).
// This round discriminates: A issued 2 iters ahead into bufA[3] (static
// parity indexing via 3-unrolled body — rule #20), unified counted wait
// vmcnt(6) covers A+B (6 VM ops/iter, 2 iters in flight), and 4 blocks/CU
// via LDS shrink. If dur unchanged -> model (1), declare roofline.
//
// Per iter t: [wait vmcnt(6): certifies A(t),B(t), keeps A(t+1),B(t+1) in
// flight] -> s_barrier (publishes slot t%3 for all waves) -> issue A(t+2)
// (4 global loads) + stage B(t+2) into slot (t+2)%3 ((t-1)%3, dead) ->
// sched_barrier -> 8 ds_read_b128 + 16 MFMA (setprio) -> sched_barrier.
__global__ __launch_bounds__(256, 4) void sync_conv_main(
    const unsigned short* __restrict__ yt, const unsigned short* __restrict__ kb,
    const int* __restrict__ ftv, const int* __restrict__ ftd,
    const float* __restrict__ bias, float* __restrict__ out) {
  // pidx is dead after phase 2; alias it over the B-ring (saves 3,136 B ->
  // 37,120 B total -> 4 blocks/CU fit in 160 KiB LDS).
  __shared__ union ShU {
    int   pidx[16][49];      //  3,136 B (prologue only)
    short ring[3 * 4096];    // 24,576 B (3 batch-slots x 8 KB)
  } sh;
  __shared__ int pre[4][16][49];   // per-wave rotated offsets  12,544 B

  int tid  = threadIdx.x;
  int lane = tid & 63;
  int w    = tid >> 6;
  int mg   = blockIdx.x >> 2;
  int lg   = blockIdx.x & 3;
  int l    = lg * 4 + w;
  int vbase = mg * 16;

  // phase 1: packed indices
  for (int t = tid; t < 16 * 48; t += 256) {
    int i = t / 48, j = t - i * 48;
    int v = vbase + i; v = v < NV ? v : NV - 1;
    sh.pidx[i][j] = ftv[v * 48 + j] * 16 + (ftd[v * 48 + j] & 15);
  }
  __syncthreads();
  // phase 2: per-l pre-rotated element offsets: vtx*1024 + ((ftd+l)&15)*64
#pragma unroll
  for (int wl = 0; wl < 4; wl++) {
    int ll = lg * 4 + wl;
    for (int t = tid; t < 768; t += 256) {
      int i = t / 48, j = t - i * 48;
      int p = sh.pidx[i][j];
      pre[wl][i][j] = (p >> 4) * 1024 + ((((p & 15) + ll) & 15) << 6);
    }
  }
  __syncthreads();   // pidx dead beyond this point; ring may overwrite it

  int q    = lane >> 4;
  int n    = lane & 15;
  int voff = n >> 1;
  int lane_elem = (n & 1) * 32 + q * 8;     // shorts
  const int* pre_w0 = &pre[w][voff][0];
  const int* pre_w1 = &pre[w][8 + voff][0];

  f32x4 acc[2][4];
#pragma unroll
  for (int i = 0; i < 2; i++)
#pragma unroll
    for (int j = 0; j < 4; j++) acc[i][j] = (f32x4){0.f, 0.f, 0.f, 0.f};

  bf16x8 bufA[3][2][2];   // [parity][mt][ds]  48 VGPR, 2 iters in flight

  // Issue the 4 A-gather loads of batch t into Ab (static parity at caller).
  auto issueA = [&](int t, bf16x8 (&Ab)[2][2]) {
    int s0 = 2 * t, s1 = s0 + 1;
    int j0 = (s0 & 48) | ((s0 + l) & 15);
    int j1 = (s1 & 48) | ((s1 + l) & 15);
    Ab[0][0] = *reinterpret_cast<const bf16x8*>(yt + pre_w0[j0] + lane_elem);
    Ab[1][0] = *reinterpret_cast<const bf16x8*>(yt + pre_w1[j0] + lane_elem);
    Ab[0][1] = *reinterpret_cast<const bf16x8*>(yt + pre_w0[j1] + lane_elem);
    Ab[1][1] = *reinterpret_cast<const bf16x8*>(yt + pre_w1[j1] + lane_elem);
  };
  // Cooperative B-stage: wave w stages its 2 KB quarter as two 1 KB
  // lane-linear gl_lds loads (per-lane global stride 16 B, LDS base uniform).
  auto stageB = [&](int t, int slot) {
    const unsigned short* g = kb + t * 4096 + w * 1024 + (lane << 3);
    short* dl = sh.ring + slot * 4096 + w * 1024;
    GLOAD16(g, dl);
    GLOAD16(g + 512, dl + 512);
  };
  auto computeT = [&](bf16x8 (&Ab)[2][2], const short* lb) {
    __builtin_amdgcn_s_setprio(1);
#pragma unroll
    for (int ds = 0; ds < 2; ds++) {
#pragma unroll
      for (int ft = 0; ft < 4; ft++) {
        bf16x8 bf = *reinterpret_cast<const bf16x8*>(lb + ds * 2048 + ft * 512 + (lane << 3));
        acc[0][ft] = __builtin_amdgcn_mfma_f32_16x16x32_bf16(Ab[0][ds], bf, acc[0][ft], 0, 0, 0);
        acc[1][ft] = __builtin_amdgcn_mfma_f32_16x16x32_bf16(Ab[1][ds], bf, acc[1][ft], 0, 0, 0);
      }
    }
    __builtin_amdgcn_s_setprio(0);
  };

  // Prologue: batches 0 and 1 fully issued (12 VM ops in flight).
  issueA(0, bufA[0]); stageB(0, 0);
  issueA(1, bufA[1]); stageB(1, 1);

#define ITER(T, PAR, PAR2)                                          \
  do {                                                              \
    if ((T) < 23) asm volatile("s_waitcnt vmcnt(6)" ::: "memory");  \
    else          asm volatile("s_waitcnt vmcnt(0)" ::: "memory");  \
    __builtin_amdgcn_s_barrier();                                   \
    if ((T) < 22) { issueA((T) + 2, bufA[PAR2]); stageB((T) + 2, PAR2); } \
    __builtin_amdgcn_sched_barrier(0);                              \
    computeT(bufA[PAR], sh.ring + (PAR) * 4096);                    \
    __builtin_amdgcn_sched_barrier(0);                              \
  } while (0)

  for (int it = 0; it < 8; it++) {
    int t0 = 3 * it;
    ITER(t0 + 0, 0, 2);
    ITER(t0 + 1, 1, 0);
    ITER(t0 + 2, 2, 1);
  }
#undef ITER

  f32x4 bv = *reinterpret_cast<const f32x4*>(bias + 4 * n);

#pragma unroll
  for (int mt = 0; mt < 2; mt++) {
#pragma unroll
    for (int reg = 0; reg < 4; reg++) {
      int m  = q * 4 + reg;
      int v  = vbase + mt * 8 + (m >> 1);
      int bb = m & 1;
      if (v < NV) {
        f32x4 x;
#pragma unroll
        for (int ft = 0; ft < 4; ft++) {
          float t = acc[mt][ft][reg] + bv[ft];   // f = 4n+ft
          x[ft] = t > 0.f ? t : 0.f;
        }
        float* dst = out + (((bb * NV + v) * ND + l) * NFDIM) + 4 * n;
        __builtin_nontemporal_store(x, (f32x4*)dst);
      }
    }
  }
}

// Slow fp32 fallback (only if ws too small).
__global__ void fallback_kernel(const float* __restrict__ y, const int* __restrict__ ftv,
                                const int* __restrict__ ftd, const float* __restrict__ kern,
                                const float* __restrict__ bias, float* __restrict__ out) {
  int idx = blockIdx.x;               // b*NV*16 + v*16 + l
  int l = idx & 15;
  int v = (idx >> 4) % NV;
  int b = idx / (NV * ND);
  int f = threadIdx.x;
  float acc = 0.f;
  for (int r = 0; r < NR; r++)
    for (int d = 0; d < ND; d++) {
      int ii = (v * NR + r) * ND + d;
      int vv = ftv[ii];
      int dd = (ftd[ii] + l) & 15;
      int dp = (d - l) & 15;
      const float* yp = y + ((b * NV + vv) * ND + dd) * NC;
      const float* kp = kern + ((r * 16 + dp) * NC) * NFDIM + f;
#pragma unroll 8
      for (int c = 0; c < NC; c++) acc += yp[c] * kp[c * NFDIM];
    }
  float x = acc + bias[f];
  out[idx * NFDIM + f] = x > 0.f ? x : 0.f;
}

extern "C" void kernel_launch(void* const* d_in, const int* in_sizes, int n_in,
                              void* d_out, int out_size, void* d_ws, size_t ws_size,
                              hipStream_t stream) {
  const float* y    = (const float*)d_in[0];
  const int*   ftv  = (const int*)d_in[1];
  const int*   ftd  = (const int*)d_in[2];
  const float* kern = (const float*)d_in[3];
  const float* bias = (const float*)d_in[4];
  float* out = (float*)d_out;

  if (ws_size >= (size_t)WS_NEEDED) {
    char* ws = (char*)d_ws;
    unsigned short* yt = (unsigned short*)ws;
    unsigned short* kb = (unsigned short*)(ws + KB_OFF);

    prep_y<<<(NV * ND * BB * NC / 8 + 255) / 256, 256, 0, stream>>>(y, (u16x8*)yt);
    prep_kb<<<(48 * 4 * 64 + 255) / 256, 256, 0, stream>>>(kern, kb);
    // 938 m-groups (16 v each) x 4 l-groups = 3752 blocks x 4 waves
    sync_conv_main<<<3752, 256, 0, stream>>>(yt, kb, ftv, ftd, bias, out);
  } else {
    fallback_kernel<<<BB * NV * ND, NFDIM, 0, stream>>>(y, ftv, ftd, kern, bias, out);
  }
}